// Round 9
// baseline (124.183 us; speedup 1.0000x reference)
//
#include <hip/hip_runtime.h>

#define BB 32
#define NN 2048
#define DD 128
#define HH 8
#define KK 64

typedef __attribute__((ext_vector_type(8))) short bf16x8;
typedef __attribute__((ext_vector_type(4))) float f32x4;
#define MFMA_BF16 __builtin_amdgcn_mfma_f32_16x16x32_bf16

// ws layout (ushort units):
//   Gp_bf : [16][32][128][128] @ 0        (8388608)  bf16 Gram partials (natural, 128-row chunks)
//   Mp_t  : [32][8][128][128]  @ 8388608  (4194304)  per-head M, TRANSPOSED [e][d]
//   Pbf   : [8][128][128]      @ 12582912 (131072)   P = Wq^T Wk (natural)

__device__ __forceinline__ float bf2f(unsigned short h){ return __uint_as_float(((unsigned)h) << 16); }
__device__ __forceinline__ unsigned short f2bf(float f){
  unsigned u = __float_as_uint(f);
  u += 0x7fffu + ((u >> 16) & 1u);   // RTNE
  return (unsigned short)(u >> 16);
}
__device__ __forceinline__ unsigned pack2(float a, float b){
  return (unsigned)f2bf(a) | ((unsigned)f2bf(b) << 16);
}

// swizzled frag load: phys_ushort(r,c) = r*128 + ((c>>3)^(r&7))*8 + (c&7)
__device__ __forceinline__ bf16x8 ldfrag_sw(const unsigned short* base, int row16, int kc, int lane){
  int d = row16 + (lane & 15);
  int q = lane >> 4;
  int ch = ((kc << 2) + q) ^ (d & 7);
  return *(const bf16x8*)(base + d*128 + ch*8);
}

// ---------------- K1: kg (blocks 0..511, 128-row chunks; 2 blocks/CU) + kp (512..543) ----------------
__global__ __launch_bounds__(512, 2) void kgkp(const float* __restrict__ x,
                                               const float* __restrict__ Wq,
                                               const float* __restrict__ Wk,
                                               unsigned short* __restrict__ Gp_bf,
                                               unsigned short* __restrict__ Pbf){
  __shared__ __align__(16) unsigned short sm[32768];   // 64 KB
  const int t = threadIdx.x;
  const int bid = blockIdx.x;
  const int w = t >> 6, lane = t & 63, quad = lane >> 4;
  if (bid < 512){
    unsigned short* xh = sm;            // hi bf16, swizzled [d][n]
    unsigned short* xl = sm + 16384;    // lo
    const int b = bid & 31, chunk = bid >> 5;          // chunk in [0,16), 128 rows
    const int wr = (w >> 1)*32, wc = (w & 1)*64;
    f32x4 acc[2][4] = {};
    const float* xb = x + ((size_t)b*NN + (size_t)chunk*128)*DD;
    for (int it = 0; it < 2; ++it){
      int gidx = it*512 + t;
      int n4g = (gidx & 7) | (((gidx >> 6) & 3) << 3);
      int dcq = ((gidx >> 3) & 7) | (((gidx >> 8) & 3) << 3);
      float4 v[4];
      #pragma unroll
      for (int j = 0; j < 4; ++j)
        v[j] = *(const float4*)(xb + (size_t)(n4g*4 + j)*DD + dcq*4);
      #pragma unroll
      for (int i = 0; i < 4; ++i){
        int d = dcq*4 + i;
        float f0 = (&v[0].x)[i], f1 = (&v[1].x)[i], f2 = (&v[2].x)[i], f3 = (&v[3].x)[i];
        unsigned short h0 = f2bf(f0), h1 = f2bf(f1), h2 = f2bf(f2), h3 = f2bf(f3);
        unsigned short l0 = f2bf(f0 - bf2f(h0)), l1 = f2bf(f1 - bf2f(h1));
        unsigned short l2 = f2bf(f2 - bf2f(h2)), l3 = f2bf(f3 - bf2f(h3));
        int off = d*128 + ((((n4g >> 1) ^ (d & 7)) << 3) + (n4g & 1)*4);
        *(ushort4*)(xh + off) = make_ushort4(h0, h1, h2, h3);
        *(ushort4*)(xl + off) = make_ushort4(l0, l1, l2, l3);
      }
    }
    __syncthreads();
    for (int kc = 0; kc < 4; ++kc){
      bf16x8 ah[2], al[2], bh[4], bl[4];
      #pragma unroll
      for (int r = 0; r < 2; ++r){
        ah[r] = ldfrag_sw(xh, wr + r*16, kc, lane);
        al[r] = ldfrag_sw(xl, wr + r*16, kc, lane);
      }
      #pragma unroll
      for (int c = 0; c < 4; ++c){
        bh[c] = ldfrag_sw(xh, wc + c*16, kc, lane);
        bl[c] = ldfrag_sw(xl, wc + c*16, kc, lane);
      }
      #pragma unroll
      for (int r = 0; r < 2; ++r)
        #pragma unroll
        for (int c = 0; c < 4; ++c){
          acc[r][c] = MFMA_BF16(ah[r], bh[c], acc[r][c], 0, 0, 0);
          acc[r][c] = MFMA_BF16(ah[r], bl[c], acc[r][c], 0, 0, 0);
          acc[r][c] = MFMA_BF16(al[r], bh[c], acc[r][c], 0, 0, 0);
        }
    }
    __syncthreads();
    float* Sf = (float*)sm;    // fp32 [128][128] = 64 KB
    #pragma unroll
    for (int r = 0; r < 2; ++r)
      #pragma unroll
      for (int c = 0; c < 4; ++c)
        #pragma unroll
        for (int reg = 0; reg < 4; ++reg)
          Sf[(wr + r*16 + quad*4 + reg)*128 + wc + c*16 + (lane & 15)] = acc[r][c][reg];
    __syncthreads();
    unsigned short* gp = Gp_bf + ((size_t)(chunk*32 + b) << 14);
    for (int i = t; i < 2048; i += 512){
      int r = i >> 4, c8 = (i & 15) * 8;
      const float* s = Sf + r*128 + c8;
      uint4 o;
      o.x = pack2(s[0], s[1]); o.y = pack2(s[2], s[3]);
      o.z = pack2(s[4], s[5]); o.w = pack2(s[6], s[7]);
      *(uint4*)(gp + r*128 + c8) = o;
    }
  } else {
    // ---- kp: P[h] = Wq^T Wk, 32 blocks, 512 threads ----
    float* Aq = (float*)sm;          // [64][36]
    float* Bk = Aq + 64*36;          // [64][132]
    const int kpid = bid - 512;
    const int h = kpid >> 2, rt = kpid & 3;
    const int i0 = rt * 32;
    const int tr = t >> 6, tc = t & 63;
    const float* wq = Wq + h*KK*DD;
    const float* wk = Wk + h*KK*DD;
    for (int i = t; i < 512; i += 512){
      int k = i >> 3, c4 = (i & 7) << 2;
      *(float4*)(&Aq[k*36 + c4]) = *(const float4*)(wq + k*DD + i0 + c4);
    }
    for (int i = t; i < 2048; i += 512){
      int k = i >> 5, c4 = (i & 31) << 2;
      *(float4*)(&Bk[k*132 + c4]) = *(const float4*)(wk + k*DD + c4);
    }
    __syncthreads();
    float acc[4][2] = {};
    for (int k = 0; k < 64; k += 2){
      float a0[4], a1[4], b0[2], b1[2];
      *(float4*)a0 = *(float4*)(&Aq[k*36 + tr*4]);
      *(float4*)a1 = *(float4*)(&Aq[(k+1)*36 + tr*4]);
      b0[0] = Bk[k*132 + tc*2];     b0[1] = Bk[k*132 + tc*2 + 1];
      b1[0] = Bk[(k+1)*132 + tc*2]; b1[1] = Bk[(k+1)*132 + tc*2 + 1];
      #pragma unroll
      for (int i = 0; i < 4; ++i)
        #pragma unroll
        for (int j = 0; j < 2; ++j){
          acc[i][j] += a0[i]*b0[j];
          acc[i][j] += a1[i]*b1[j];
        }
    }
    unsigned short* Ph = Pbf + h*DD*DD;
    #pragma unroll
    for (int i = 0; i < 4; ++i)
      *(ushort2*)(&Ph[(i0 + tr*4 + i)*DD + tc*2]) =
          make_ushort2(f2bf(acc[i][0]), f2bf(acc[i][1]));
  }
}

// ---------------- K2: per (b,h): reduce 16 Gp->G; T = G@Wv^T; M = P@T; write M TRANSPOSED ----------------
__global__ __launch_bounds__(512, 2) void km2(const unsigned short* __restrict__ Gp_bf,
                                              const float* __restrict__ Wv,
                                              const unsigned short* __restrict__ Pbf,
                                              unsigned short* __restrict__ Mp_t){
  __shared__ __align__(16) unsigned short sm[32768];   // As | Bs, 64 KB
  unsigned short* As = sm;           // G then P, swizzled [d][k]
  unsigned short* Bs = sm + 16384;   // Wv then T^T, swizzled [e][k]
  const int bid = blockIdx.x;
  const int b = bid & 31, h = bid >> 5;
  const int t = threadIdx.x;
  const int w = t >> 6, lane = t & 63, quad = lane >> 4;
  // reduce 16 bf16 G-partials (fp32, ascending chunk order) -> As swizzled
  for (int i = t; i < 2048; i += 512){
    int r = i >> 4, c8 = (i & 15) * 8;
    float s[8] = {};
    #pragma unroll
    for (int p = 0; p < 16; ++p){
      uint4 u = *(const uint4*)(Gp_bf + (((size_t)(p*32 + b)) << 14) + r*128 + c8);
      const unsigned short* pu = (const unsigned short*)&u;
      #pragma unroll
      for (int j = 0; j < 8; ++j) s[j] += bf2f(pu[j]);
    }
    uint4 o;
    o.x = pack2(s[0], s[1]); o.y = pack2(s[2], s[3]);
    o.z = pack2(s[4], s[5]); o.w = pack2(s[6], s[7]);
    *(uint4*)(As + r*128 + ((((c8 >> 3) ^ (r & 7))) << 3)) = o;
  }
  // stage Wv[h] full (cvt bf16, swizzled [e][d'])
  const float* Wvh = Wv + (size_t)h*DD*DD;
  for (int i = t; i < 4096; i += 512){
    int e = i >> 5, dc = (i & 31) * 4;
    float4 v = *(const float4*)(Wvh + (size_t)e*DD + dc);
    int off = e*128 + ((((dc >> 3) ^ (e & 7)) << 3) + (dc & 4));
    *(ushort4*)(Bs + off) = make_ushort4(f2bf(v.x), f2bf(v.y), f2bf(v.z), f2bf(v.w));
  }
  __syncthreads();
  // phase 1: T[d][e] = G @ Wv^T; wave w owns d-tile w, all 8 e-tiles
  f32x4 acc1[8] = {};
  for (int kc = 0; kc < 4; ++kc){
    bf16x8 a = ldfrag_sw(As, w*16, kc, lane);
    bf16x8 bb[8];
    #pragma unroll
    for (int c = 0; c < 8; ++c) bb[c] = ldfrag_sw(Bs, c*16, kc, lane);
    #pragma unroll
    for (int c = 0; c < 8; ++c) acc1[c] = MFMA_BF16(a, bb[c], acc1[c], 0, 0, 0);
  }
  __syncthreads();
  // write T^T into Bs (swizzled [e][c]); stage P into As
  #pragma unroll
  for (int c = 0; c < 8; ++c){
    int e = c*16 + (lane & 15);
    int d0 = w*16 + quad*4;
    int off = e*128 + ((((d0 >> 3) ^ (e & 7)) << 3) + (d0 & 7));
    *(ushort4*)(Bs + off) = make_ushort4(f2bf(acc1[c][0]), f2bf(acc1[c][1]),
                                         f2bf(acc1[c][2]), f2bf(acc1[c][3]));
  }
  const unsigned short* Ph = Pbf + (size_t)h*DD*DD;
  for (int i = t; i < 2048; i += 512){
    int r = i >> 4, ch = i & 15;
    *(uint4*)(As + r*128 + ((ch ^ (r & 7)) << 3)) = *(const uint4*)(Ph + r*128 + ch*8);
  }
  __syncthreads();
  // phase 2: M[d][e] = P @ T
  f32x4 acc2[8] = {};
  for (int kc = 0; kc < 4; ++kc){
    bf16x8 a = ldfrag_sw(As, w*16, kc, lane);
    bf16x8 bb[8];
    #pragma unroll
    for (int c = 0; c < 8; ++c) bb[c] = ldfrag_sw(Bs, c*16, kc, lane);
    #pragma unroll
    for (int c = 0; c < 8; ++c) acc2[c] = MFMA_BF16(a, bb[c], acc2[c], 0, 0, 0);
  }
  __syncthreads();
  // epilogue: TRANSPOSED repack through fp32 LDS -> coalesced bf16 store of M^T [e][d]
  float* Sf = (float*)sm;   // [e][d] 128x128 fp32 = 64 KB
  #pragma unroll
  for (int c = 0; c < 8; ++c){
    int e = c*16 + (lane & 15);
    int xr = (e & 7) << 2;
    #pragma unroll
    for (int reg = 0; reg < 4; ++reg){
      int d = w*16 + quad*4 + reg;
      Sf[e*128 + (d ^ xr)] = acc2[c][reg];
    }
  }
  __syncthreads();
  unsigned short* Mb = Mp_t + (((size_t)(b*8 + h)) << 14);
  for (int i = t; i < 2048; i += 512){
    int e = i >> 4, c8 = (i & 15) * 8;
    int xr = (e & 7) << 2;
    float4 lo = *(const float4*)(Sf + e*128 + (c8 ^ xr));
    float4 hi = *(const float4*)(Sf + e*128 + ((c8 + 4) ^ xr));
    uint4 o;
    o.x = pack2(lo.x, lo.y); o.y = pack2(lo.z, lo.w);
    o.z = pack2(hi.x, hi.y); o.w = pack2(hi.z, hi.w);
    *(uint4*)(Mb + e*128 + c8) = o;
  }
}

// ---------------- K3: ko — out[b,nt] = x_tile @ M; Ms staged by inline h-reduce of Mp_t ----------------
__global__ __launch_bounds__(512, 4) void ko2(const float* __restrict__ x,
                                              const unsigned short* __restrict__ Mp_t,
                                              float* __restrict__ out){
  __shared__ __align__(16) unsigned short sm[32768];   // xs | Ms; epilogue float [n][128]
  unsigned short* xs = sm;           // x tile bf16, swizzled [n][d]
  unsigned short* Ms = sm + 16384;   // M^T bf16, swizzled [e][d]
  const int bid = blockIdx.x;
  const int b = bid & 31, nt = bid >> 5;
  const int t = threadIdx.x;
  const int w = t >> 6, lane = t & 63, quad = lane >> 4;
  const float* xb = x + ((size_t)b*NN + (size_t)nt*128)*DD;
  for (int i = t; i < 4096; i += 512){
    int n = i >> 5, dcq = i & 31;
    float4 v = *(const float4*)(xb + (size_t)n*DD + dcq*4);
    int off = n*128 + ((((dcq >> 1) ^ (n & 7)) << 3) + (dcq & 1)*4);
    *(ushort4*)(xs + off) = make_ushort4(f2bf(v.x), f2bf(v.y), f2bf(v.z), f2bf(v.w));
  }
  // stage Ms: sum 8 per-head M^T (bf16 -> fp32, h ascending) -> bf16 swizzled
  const unsigned short* Mpb = Mp_t + (((size_t)b * 8) << 14);
  for (int i = t; i < 2048; i += 512){
    int e = i >> 4, dch = i & 15;
    float s[8] = {};
    #pragma unroll
    for (int hh = 0; hh < 8; ++hh){
      uint4 u = *(const uint4*)(Mpb + ((size_t)hh << 14) + e*128 + dch*8);
      const unsigned short* pu = (const unsigned short*)&u;
      #pragma unroll
      for (int j = 0; j < 8; ++j) s[j] += bf2f(pu[j]);
    }
    uint4 o;
    o.x = pack2(s[0], s[1]); o.y = pack2(s[2], s[3]);
    o.z = pack2(s[4], s[5]); o.w = pack2(s[6], s[7]);
    *(uint4*)(Ms + e*128 + ((dch ^ (e & 7)) << 3)) = o;
  }
  __syncthreads();
  const int wr = (w >> 1)*32, wc = (w & 1)*64;
  f32x4 acc[2][4] = {};
  for (int kc = 0; kc < 4; ++kc){
    bf16x8 a[2], bb[4];
    #pragma unroll
    for (int r = 0; r < 2; ++r) a[r] = ldfrag_sw(xs, wr + r*16, kc, lane);
    #pragma unroll
    for (int c = 0; c < 4; ++c) bb[c] = ldfrag_sw(Ms, wc + c*16, kc, lane);
    #pragma unroll
    for (int r = 0; r < 2; ++r)
      #pragma unroll
      for (int c = 0; c < 4; ++c)
        acc[r][c] = MFMA_BF16(a[r], bb[c], acc[r][c], 0, 0, 0);
  }
  __syncthreads();
  float* Sf = (float*)sm;   // [n][128] fp32, 64 KB
  #pragma unroll
  for (int r = 0; r < 2; ++r)
    #pragma unroll
    for (int c = 0; c < 4; ++c)
      #pragma unroll
      for (int reg = 0; reg < 4; ++reg)
        Sf[(wr + r*16 + quad*4 + reg)*128 + wc + c*16 + (lane & 15)] = acc[r][c][reg];
  __syncthreads();
  float* ob = out + ((size_t)b*NN + (size_t)nt*128)*DD;
  for (int i = t; i < 4096; i += 512){
    int n = i >> 5, c4 = (i & 31) * 4;
    *(float4*)(ob + (size_t)n*DD + c4) = *(const float4*)(Sf + n*128 + c4);
  }
}

extern "C" void kernel_launch(void* const* d_in, const int* in_sizes, int n_in,
                              void* d_out, int out_size, void* d_ws, size_t ws_size,
                              hipStream_t stream){
  const float* x  = (const float*)d_in[0];
  const float* Wk = (const float*)d_in[1];
  const float* Wq = (const float*)d_in[2];
  const float* Wv = (const float*)d_in[3];
  float* out = (float*)d_out;
  unsigned short* wsu = (unsigned short*)d_ws;
  unsigned short* Gp_bf = wsu;               // 8388608
  unsigned short* Mp_t  = wsu + 8388608;     // 4194304
  unsigned short* Pbf   = wsu + 12582912;    // 131072

  kgkp<<<544, 512, 0, stream>>>(x, Wq, Wk, Gp_bf, Pbf);
  km2 <<<256, 512, 0, stream>>>(Gp_bf, Wv, Pbf, Mp_t);
  ko2 <<<512, 512, 0, stream>>>(x, Mp_t, out);
}

// Round 10
// 120.417 us; speedup vs baseline: 1.0313x; 1.0313x over previous
//
#include <hip/hip_runtime.h>

#define BB 32
#define NN 2048
#define DD 128
#define HH 8
#define KK 64

typedef __attribute__((ext_vector_type(8))) short bf16x8;
typedef __attribute__((ext_vector_type(4))) float f32x4;
#define MFMA_BF16 __builtin_amdgcn_mfma_f32_16x16x32_bf16

// ws layout (ushort units):
//   Gp_bf : [8][32][128][128]  @ 0        (4194304)  bf16 Gram partials (natural)
//   Mp_t  : [32][8][128][128]  @ 4194304  (4194304)  per-head M, TRANSPOSED [e][d]
//   Pbf   : [8][128][128]      @ 8388608  (131072)   P = Wq^T Wk (natural)

__device__ __forceinline__ float bf2f(unsigned short h){ return __uint_as_float(((unsigned)h) << 16); }
__device__ __forceinline__ unsigned short f2bf(float f){
  unsigned u = __float_as_uint(f);
  u += 0x7fffu + ((u >> 16) & 1u);   // RTNE
  return (unsigned short)(u >> 16);
}
__device__ __forceinline__ unsigned pack2(float a, float b){
  return (unsigned)f2bf(a) | ((unsigned)f2bf(b) << 16);
}

// swizzled frag load: phys_ushort(r,c) = r*128 + ((c>>3)^(r&7))*8 + (c&7)
__device__ __forceinline__ bf16x8 ldfrag_sw(const unsigned short* base, int row16, int kc, int lane){
  int d = row16 + (lane & 15);
  int q = lane >> 4;
  int ch = ((kc << 2) + q) ^ (d & 7);
  return *(const bf16x8*)(base + d*128 + ch*8);
}

// ---------------- K1: kg (blocks 0..255, 256-row chunks) + kp (256..287) ----------------
__global__ __launch_bounds__(512, 4) void kgkp(const float* __restrict__ x,
                                               const float* __restrict__ Wq,
                                               const float* __restrict__ Wk,
                                               unsigned short* __restrict__ Gp_bf,
                                               unsigned short* __restrict__ Pbf){
  __shared__ __align__(16) unsigned short sm[32768];   // 64 KB
  const int t = threadIdx.x;
  const int bid = blockIdx.x;
  const int w = t >> 6, lane = t & 63, quad = lane >> 4;
  if (bid < 256){
    unsigned short* xh = sm;            // hi bf16, swizzled [d][n]
    unsigned short* xl = sm + 16384;    // lo
    const int b = bid & 31, chunk = bid >> 5;          // chunk in [0,8), 256 rows
    const int wr = (w >> 1)*32, wc = (w & 1)*64;
    f32x4 acc[2][4] = {};
    for (int sub = 0; sub < 2; ++sub){
      if (sub) __syncthreads();
      const float* xb = x + ((size_t)b*NN + (size_t)(chunk*256 + sub*128))*DD;
      for (int it = 0; it < 2; ++it){
        int gidx = it*512 + t;
        int n4g = (gidx & 7) | (((gidx >> 6) & 3) << 3);
        int dcq = ((gidx >> 3) & 7) | (((gidx >> 8) & 3) << 3);
        float4 v[4];
        #pragma unroll
        for (int j = 0; j < 4; ++j)
          v[j] = *(const float4*)(xb + (size_t)(n4g*4 + j)*DD + dcq*4);
        #pragma unroll
        for (int i = 0; i < 4; ++i){
          int d = dcq*4 + i;
          float f0 = (&v[0].x)[i], f1 = (&v[1].x)[i], f2 = (&v[2].x)[i], f3 = (&v[3].x)[i];
          unsigned short h0 = f2bf(f0), h1 = f2bf(f1), h2 = f2bf(f2), h3 = f2bf(f3);
          unsigned short l0 = f2bf(f0 - bf2f(h0)), l1 = f2bf(f1 - bf2f(h1));
          unsigned short l2 = f2bf(f2 - bf2f(h2)), l3 = f2bf(f3 - bf2f(h3));
          int off = d*128 + ((((n4g >> 1) ^ (d & 7)) << 3) + (n4g & 1)*4);
          *(ushort4*)(xh + off) = make_ushort4(h0, h1, h2, h3);
          *(ushort4*)(xl + off) = make_ushort4(l0, l1, l2, l3);
        }
      }
      __syncthreads();
      for (int kc = 0; kc < 4; ++kc){
        bf16x8 ah[2], al[2], bh[4], bl[4];
        #pragma unroll
        for (int r = 0; r < 2; ++r){
          ah[r] = ldfrag_sw(xh, wr + r*16, kc, lane);
          al[r] = ldfrag_sw(xl, wr + r*16, kc, lane);
        }
        #pragma unroll
        for (int c = 0; c < 4; ++c){
          bh[c] = ldfrag_sw(xh, wc + c*16, kc, lane);
          bl[c] = ldfrag_sw(xl, wc + c*16, kc, lane);
        }
        #pragma unroll
        for (int r = 0; r < 2; ++r)
          #pragma unroll
          for (int c = 0; c < 4; ++c){
            acc[r][c] = MFMA_BF16(ah[r], bh[c], acc[r][c], 0, 0, 0);
            acc[r][c] = MFMA_BF16(ah[r], bl[c], acc[r][c], 0, 0, 0);
            acc[r][c] = MFMA_BF16(al[r], bh[c], acc[r][c], 0, 0, 0);
          }
      }
    }
    __syncthreads();
    float* Sf = (float*)sm;    // fp32 [128][128] = 64 KB
    #pragma unroll
    for (int r = 0; r < 2; ++r)
      #pragma unroll
      for (int c = 0; c < 4; ++c)
        #pragma unroll
        for (int reg = 0; reg < 4; ++reg)
          Sf[(wr + r*16 + quad*4 + reg)*128 + wc + c*16 + (lane & 15)] = acc[r][c][reg];
    __syncthreads();
    unsigned short* gp = Gp_bf + ((size_t)(chunk*32 + b) << 14);
    for (int i = t; i < 2048; i += 512){
      int r = i >> 4, c8 = (i & 15) * 8;
      const float* s = Sf + r*128 + c8;
      uint4 o;
      o.x = pack2(s[0], s[1]); o.y = pack2(s[2], s[3]);
      o.z = pack2(s[4], s[5]); o.w = pack2(s[6], s[7]);
      *(uint4*)(gp + r*128 + c8) = o;
    }
  } else {
    // ---- kp: P[h] = Wq^T Wk, 32 blocks, 512 threads ----
    float* Aq = (float*)sm;          // [64][36]
    float* Bk = Aq + 64*36;          // [64][132]
    const int kpid = bid - 256;
    const int h = kpid >> 2, rt = kpid & 3;
    const int i0 = rt * 32;
    const int tr = t >> 6, tc = t & 63;
    const float* wq = Wq + h*KK*DD;
    const float* wk = Wk + h*KK*DD;
    for (int i = t; i < 512; i += 512){
      int k = i >> 3, c4 = (i & 7) << 2;
      *(float4*)(&Aq[k*36 + c4]) = *(const float4*)(wq + k*DD + i0 + c4);
    }
    for (int i = t; i < 2048; i += 512){
      int k = i >> 5, c4 = (i & 31) << 2;
      *(float4*)(&Bk[k*132 + c4]) = *(const float4*)(wk + k*DD + c4);
    }
    __syncthreads();
    float acc[4][2] = {};
    for (int k = 0; k < 64; k += 2){
      float a0[4], a1[4], b0[2], b1[2];
      *(float4*)a0 = *(float4*)(&Aq[k*36 + tr*4]);
      *(float4*)a1 = *(float4*)(&Aq[(k+1)*36 + tr*4]);
      b0[0] = Bk[k*132 + tc*2];     b0[1] = Bk[k*132 + tc*2 + 1];
      b1[0] = Bk[(k+1)*132 + tc*2]; b1[1] = Bk[(k+1)*132 + tc*2 + 1];
      #pragma unroll
      for (int i = 0; i < 4; ++i)
        #pragma unroll
        for (int j = 0; j < 2; ++j){
          acc[i][j] += a0[i]*b0[j];
          acc[i][j] += a1[i]*b1[j];
        }
    }
    unsigned short* Ph = Pbf + h*DD*DD;
    #pragma unroll
    for (int i = 0; i < 4; ++i)
      *(ushort2*)(&Ph[(i0 + tr*4 + i)*DD + tc*2]) =
          make_ushort2(f2bf(acc[i][0]), f2bf(acc[i][1]));
  }
}

// ---------------- K2: per (b,h): reduce Gp->G; T = G@Wv^T; M = P@T; write M TRANSPOSED ----------------
__global__ __launch_bounds__(512, 2) void km2(const unsigned short* __restrict__ Gp_bf,
                                              const float* __restrict__ Wv,
                                              const unsigned short* __restrict__ Pbf,
                                              unsigned short* __restrict__ Mp_t){
  __shared__ __align__(16) unsigned short sm[32768];   // As | Bs, 64 KB
  unsigned short* As = sm;           // G then P, swizzled [d][k]
  unsigned short* Bs = sm + 16384;   // Wv then T^T, swizzled [e][k]
  const int bid = blockIdx.x;
  const int b = bid & 31, h = bid >> 5;
  const int t = threadIdx.x;
  const int w = t >> 6, lane = t & 63, quad = lane >> 4;
  // reduce 8 bf16 G-partials (fp32) -> As swizzled
  for (int i = t; i < 2048; i += 512){
    int r = i >> 4, c8 = (i & 15) * 8;
    float s[8] = {};
    #pragma unroll
    for (int p = 0; p < 8; ++p){
      uint4 u = *(const uint4*)(Gp_bf + (((size_t)(p*32 + b)) << 14) + r*128 + c8);
      const unsigned short* pu = (const unsigned short*)&u;
      #pragma unroll
      for (int j = 0; j < 8; ++j) s[j] += bf2f(pu[j]);
    }
    uint4 o;
    o.x = pack2(s[0], s[1]); o.y = pack2(s[2], s[3]);
    o.z = pack2(s[4], s[5]); o.w = pack2(s[6], s[7]);
    *(uint4*)(As + r*128 + ((((c8 >> 3) ^ (r & 7))) << 3)) = o;
  }
  // stage Wv[h] full (cvt bf16, swizzled [e][d'])
  const float* Wvh = Wv + (size_t)h*DD*DD;
  for (int i = t; i < 4096; i += 512){
    int e = i >> 5, dc = (i & 31) * 4;
    float4 v = *(const float4*)(Wvh + (size_t)e*DD + dc);
    int off = e*128 + ((((dc >> 3) ^ (e & 7)) << 3) + (dc & 4));
    *(ushort4*)(Bs + off) = make_ushort4(f2bf(v.x), f2bf(v.y), f2bf(v.z), f2bf(v.w));
  }
  __syncthreads();
  // phase 1: T[d][e] = G @ Wv^T; wave w owns d-tile w, all 8 e-tiles
  f32x4 acc1[8] = {};
  for (int kc = 0; kc < 4; ++kc){
    bf16x8 a = ldfrag_sw(As, w*16, kc, lane);
    bf16x8 bb[8];
    #pragma unroll
    for (int c = 0; c < 8; ++c) bb[c] = ldfrag_sw(Bs, c*16, kc, lane);
    #pragma unroll
    for (int c = 0; c < 8; ++c) acc1[c] = MFMA_BF16(a, bb[c], acc1[c], 0, 0, 0);
  }
  __syncthreads();
  // write T^T into Bs (swizzled [e][c]); stage P into As
  #pragma unroll
  for (int c = 0; c < 8; ++c){
    int e = c*16 + (lane & 15);
    int d0 = w*16 + quad*4;
    int off = e*128 + ((((d0 >> 3) ^ (e & 7)) << 3) + (d0 & 7));
    *(ushort4*)(Bs + off) = make_ushort4(f2bf(acc1[c][0]), f2bf(acc1[c][1]),
                                         f2bf(acc1[c][2]), f2bf(acc1[c][3]));
  }
  const unsigned short* Ph = Pbf + (size_t)h*DD*DD;
  for (int i = t; i < 2048; i += 512){
    int r = i >> 4, ch = i & 15;
    *(uint4*)(As + r*128 + ((ch ^ (r & 7)) << 3)) = *(const uint4*)(Ph + r*128 + ch*8);
  }
  __syncthreads();
  // phase 2: M[d][e] = P @ T
  f32x4 acc2[8] = {};
  for (int kc = 0; kc < 4; ++kc){
    bf16x8 a = ldfrag_sw(As, w*16, kc, lane);
    bf16x8 bb[8];
    #pragma unroll
    for (int c = 0; c < 8; ++c) bb[c] = ldfrag_sw(Bs, c*16, kc, lane);
    #pragma unroll
    for (int c = 0; c < 8; ++c) acc2[c] = MFMA_BF16(a, bb[c], acc2[c], 0, 0, 0);
  }
  __syncthreads();
  // epilogue: TRANSPOSED repack through fp32 LDS -> coalesced bf16 store of M^T [e][d]
  // LDS col swizzled by ((e&7)<<2) to break the all-lanes-same-column bank conflict
  float* Sf = (float*)sm;   // [e][d] 128x128 fp32 = 64 KB
  #pragma unroll
  for (int c = 0; c < 8; ++c){
    int e = c*16 + (lane & 15);
    int xr = (e & 7) << 2;
    #pragma unroll
    for (int reg = 0; reg < 4; ++reg){
      int d = w*16 + quad*4 + reg;
      Sf[e*128 + (d ^ xr)] = acc2[c][reg];
    }
  }
  __syncthreads();
  unsigned short* Mb = Mp_t + (((size_t)(b*8 + h)) << 14);
  for (int i = t; i < 2048; i += 512){
    int e = i >> 4, c8 = (i & 15) * 8;
    int xr = (e & 7) << 2;
    float4 lo = *(const float4*)(Sf + e*128 + (c8 ^ xr));
    float4 hi = *(const float4*)(Sf + e*128 + ((c8 + 4) ^ xr));
    uint4 o;
    o.x = pack2(lo.x, lo.y); o.y = pack2(lo.z, lo.w);
    o.z = pack2(hi.x, hi.y); o.w = pack2(hi.z, hi.w);
    *(uint4*)(Mb + e*128 + c8) = o;
  }
}

// ---------------- K3: ko — out[b,nt] = x_tile @ M; Ms staged by inline h-reduce of Mp_t ----------------
__global__ __launch_bounds__(512, 4) void ko2(const float* __restrict__ x,
                                              const unsigned short* __restrict__ Mp_t,
                                              float* __restrict__ out){
  __shared__ __align__(16) unsigned short sm[32768];   // xs | Ms; epilogue float [n][128]
  unsigned short* xs = sm;           // x tile bf16, swizzled [n][d]
  unsigned short* Ms = sm + 16384;   // M^T bf16, swizzled [e][d]
  const int bid = blockIdx.x;
  const int b = bid & 31, nt = bid >> 5;
  const int t = threadIdx.x;
  const int w = t >> 6, lane = t & 63, quad = lane >> 4;
  const float* xb = x + ((size_t)b*NN + (size_t)nt*128)*DD;
  for (int i = t; i < 4096; i += 512){
    int n = i >> 5, dcq = i & 31;
    float4 v = *(const float4*)(xb + (size_t)n*DD + dcq*4);
    int off = n*128 + ((((dcq >> 1) ^ (n & 7)) << 3) + (dcq & 1)*4);
    *(ushort4*)(xs + off) = make_ushort4(f2bf(v.x), f2bf(v.y), f2bf(v.z), f2bf(v.w));
  }
  // stage Ms: sum 8 per-head M^T (bf16 -> fp32, h ascending) -> bf16 swizzled
  const unsigned short* Mpb = Mp_t + (((size_t)b * 8) << 14);
  for (int i = t; i < 2048; i += 512){
    int e = i >> 4, dch = i & 15;
    float s[8] = {};
    #pragma unroll
    for (int hh = 0; hh < 8; ++hh){
      uint4 u = *(const uint4*)(Mpb + ((size_t)hh << 14) + e*128 + dch*8);
      const unsigned short* pu = (const unsigned short*)&u;
      #pragma unroll
      for (int j = 0; j < 8; ++j) s[j] += bf2f(pu[j]);
    }
    uint4 o;
    o.x = pack2(s[0], s[1]); o.y = pack2(s[2], s[3]);
    o.z = pack2(s[4], s[5]); o.w = pack2(s[6], s[7]);
    *(uint4*)(Ms + e*128 + ((dch ^ (e & 7)) << 3)) = o;
  }
  __syncthreads();
  const int wr = (w >> 1)*32, wc = (w & 1)*64;
  f32x4 acc[2][4] = {};
  for (int kc = 0; kc < 4; ++kc){
    bf16x8 a[2], bb[4];
    #pragma unroll
    for (int r = 0; r < 2; ++r) a[r] = ldfrag_sw(xs, wr + r*16, kc, lane);
    #pragma unroll
    for (int c = 0; c < 4; ++c) bb[c] = ldfrag_sw(Ms, wc + c*16, kc, lane);
    #pragma unroll
    for (int r = 0; r < 2; ++r)
      #pragma unroll
      for (int c = 0; c < 4; ++c)
        acc[r][c] = MFMA_BF16(a[r], bb[c], acc[r][c], 0, 0, 0);
  }
  __syncthreads();
  float* Sf = (float*)sm;   // [n][128] fp32, 64 KB
  #pragma unroll
  for (int r = 0; r < 2; ++r)
    #pragma unroll
    for (int c = 0; c < 4; ++c)
      #pragma unroll
      for (int reg = 0; reg < 4; ++reg)
        Sf[(wr + r*16 + quad*4 + reg)*128 + wc + c*16 + (lane & 15)] = acc[r][c][reg];
  __syncthreads();
  float* ob = out + ((size_t)b*NN + (size_t)nt*128)*DD;
  for (int i = t; i < 4096; i += 512){
    int n = i >> 5, c4 = (i & 31) * 4;
    *(float4*)(ob + (size_t)n*DD + c4) = *(const float4*)(Sf + n*128 + c4);
  }
}

extern "C" void kernel_launch(void* const* d_in, const int* in_sizes, int n_in,
                              void* d_out, int out_size, void* d_ws, size_t ws_size,
                              hipStream_t stream){
  const float* x  = (const float*)d_in[0];
  const float* Wk = (const float*)d_in[1];
  const float* Wq = (const float*)d_in[2];
  const float* Wv = (const float*)d_in[3];
  float* out = (float*)d_out;
  unsigned short* wsu = (unsigned short*)d_ws;
  unsigned short* Gp_bf = wsu;               // 4194304
  unsigned short* Mp_t  = wsu + 4194304;     // 4194304
  unsigned short* Pbf   = wsu + 8388608;     // 131072

  kgkp<<<288, 512, 0, stream>>>(x, Wq, Wk, Gp_bf, Pbf);
  km2 <<<256, 512, 0, stream>>>(Gp_bf, Wv, Pbf, Mp_t);
  ko2 <<<512, 512, 0, stream>>>(x, Mp_t, out);
}